// Round 10
// baseline (107.489 us; speedup 1.0000x reference)
//
#include <hip/hip_runtime.h>

// Problem constants (fixed by setup_inputs): B=8, H=W=512, D=32, K=64
#define B_    8
#define N_    (512 * 512)
#define D_    32
#define K_    64
#define TPB   256
#define NWAVE (TPB / 64)
#define NPAIR (TPB / 128)        // 2 wave-pairs per block
#define KROW  36                 // row stride (floats): 16B-aligned, spreads banks
#define TABW  (K_ * KROW)        // 2304 floats per PAIR-shared table
#define REC   (K_ * D_ + K_)     // per-block partial record: 2048 sums + 64 counts
#define RECQ  (REC / 4)          // 528 float4 quads per record

// ---------------------------------------------------------------------------
// Stage 1: per-block partial segment sums, PAIR-SPLIT tables for 2x occupancy.
// Two waves share one table: wave hi=0 owns float columns 0-15, hi=1 owns
// 16-31 (disjoint b128 ranges -> race-free across waves, no atomics needed
// between them). Each wave: 16 elements x 4 lanes (one float4 each).
// LDS/block: 2 tables = ~19 KB -> 8 blocks/CU = 32 waves/CU (100%).
// Duplicate handling as proven r5/r6: order==0 lane does plain b128 RMW;
// order>0 lanes (~11% of elements at 16-wide) issue ds_add atomics AFTER the
// write in program order (same-wave LDS ops complete in issue order).
// Counts: czen lanes (hi==0, q==0) ds-atomic += 1 each iteration.
// 2-deep pipeline with macro-expanded NAMED registers (r4 scratch lesson).
// ---------------------------------------------------------------------------
#define PROC16(L0,L1,L2,L3,L4,L5,L6,L7,L8,L9,L10,L11,L12,L13,L14,L15, V, PBASE) \
  {                                                                           \
    int lb = el < 8                                                           \
      ? (el < 4 ? (el < 2 ? (el == 0 ? L0 : L1) : (el == 2 ? L2 : L3))        \
                : (el < 6 ? (el == 4 ? L4 : L5) : (el == 6 ? L6 : L7)))       \
      : (el < 12 ? (el < 10 ? (el == 8 ? L8 : L9) : (el == 10 ? L10 : L11))   \
                 : (el < 14 ? (el == 12 ? L12 : L13)                          \
                            : (el == 14 ? L14 : L15)));                       \
    const int m0 = (lb == L0),  m1 = (lb == L1),  m2 = (lb == L2),            \
              m3 = (lb == L3),  m4 = (lb == L4),  m5 = (lb == L5),            \
              m6 = (lb == L6),  m7 = (lb == L7),  m8 = (lb == L8),            \
              m9 = (lb == L9),  m10 = (lb == L10), m11 = (lb == L11),         \
              m12 = (lb == L12), m13 = (lb == L13), m14 = (lb == L14);        \
    const int order = (g0 & m0) + (g1 & m1) + (g2 & m2) + (g3 & m3) +         \
                      (g4 & m4) + (g5 & m5) + (g6 & m6) + (g7 & m7) +         \
                      (g8 & m8) + (g9 & m9) + (g10 & m10) + (g11 & m11) +     \
                      (g12 & m12) + (g13 & m13) + (g14 & m14);                \
    const float4 vc = V;                                                      \
    const int pb = (PBASE);                                                   \
    if (pb < N_) {        /* uniform branch */                                \
      const int* lp = lab + bbase + pb + wb;   /* wave-uniform -> s_load */   \
      L0 = lp[0];  L1 = lp[1];  L2 = lp[2];  L3 = lp[3];                      \
      L4 = lp[4];  L5 = lp[5];  L6 = lp[6];  L7 = lp[7];                      \
      L8 = lp[8];  L9 = lp[9];  L10 = lp[10]; L11 = lp[11];                   \
      L12 = lp[12]; L13 = lp[13]; L14 = lp[14]; L15 = lp[15];                 \
      V = embv[(bbase + pb + eg) * 8 + d4];                                   \
    }                                                                         \
    const int a = lb * KROW + d4 * 4;                                         \
    if (czen) atomicAdd(&cnt[lb], 1.0f);                                      \
    if (order == 0) {                                                         \
      float4 cur = *reinterpret_cast<const float4*>(tab + a);                 \
      cur.x += vc.x; cur.y += vc.y; cur.z += vc.z; cur.w += vc.w;             \
      *reinterpret_cast<float4*>(tab + a) = cur;                              \
    } else {  /* rare; lands after the write in issue order */                \
      atomicAdd(&tab[a + 0], vc.x);                                           \
      atomicAdd(&tab[a + 1], vc.y);                                           \
      atomicAdd(&tab[a + 2], vc.z);                                           \
      atomicAdd(&tab[a + 3], vc.w);                                           \
    }                                                                         \
  }

#define LOADSET16(L0,L1,L2,L3,L4,L5,L6,L7,L8,L9,L10,L11,L12,L13,L14,L15, V, BASE) \
  if ((BASE) < N_) {                                                          \
    const int* lp = lab + bbase + (BASE) + wb;                                \
    L0 = lp[0];  L1 = lp[1];  L2 = lp[2];  L3 = lp[3];                        \
    L4 = lp[4];  L5 = lp[5];  L6 = lp[6];  L7 = lp[7];                        \
    L8 = lp[8];  L9 = lp[9];  L10 = lp[10]; L11 = lp[11];                     \
    L12 = lp[12]; L13 = lp[13]; L14 = lp[14]; L15 = lp[15];                   \
    V = embv[(bbase + (BASE) + eg) * 8 + d4];                                 \
  }

__global__ __launch_bounds__(TPB, 8) void seg_partial_kernel(
    const float* __restrict__ emb, const int* __restrict__ lab,
    float* __restrict__ partials, int blk_per_b)
{
    __shared__ __align__(16) float s_tab[NPAIR * TABW];
    __shared__ float s_cnt[NPAIR * K_];

    for (int i = threadIdx.x; i < NPAIR * TABW; i += TPB) s_tab[i] = 0.f;
    for (int i = threadIdx.x; i < NPAIR * K_;  i += TPB) s_cnt[i] = 0.f;
    __syncthreads();

    const int tid  = threadIdx.x;
    const int wave = tid >> 6;
    const int pair = wave >> 1;          // 0..1: which table
    const int hi   = wave & 1;           // 0: cols 0-15, 1: cols 16-31
    const int lane = tid & 63;
    const int el   = lane >> 2;          // element slot within pair: 0..15
    const int q    = lane & 3;           // quad within my dim-half: 0..3
    const int d4   = q + 4 * hi;         // float4 slice within element: 0..7
    const int eg   = pair * 16 + el;     // element slot within block-iter: 0..31
    const int czen = (hi == 0) && (q == 0);

    // loop-invariant "slot i is earlier than mine" predicates
    const int g0 = (0 < el),  g1 = (1 < el),  g2 = (2 < el),  g3 = (3 < el),
              g4 = (4 < el),  g5 = (5 < el),  g6 = (6 < el),  g7 = (7 < el),
              g8 = (8 < el),  g9 = (9 < el),  g10 = (10 < el),
              g11 = (11 < el), g12 = (12 < el), g13 = (13 < el),
              g14 = (14 < el);

    float* __restrict__ tab = s_tab + pair * TABW;
    float* __restrict__ cnt = s_cnt + pair * K_;

    const int blk = blockIdx.x;
    const int b   = blk / blk_per_b;
    const int bib = blk - b * blk_per_b;
    const long long bbase = (long long)b * N_;
    const float4* __restrict__ embv = reinterpret_cast<const float4*>(emb);
    const int STEP = blk_per_b * 32;
    const int wb = __builtin_amdgcn_readfirstlane(pair * 16);

    int ib = bib * 32;

    // prologue: fill both pipeline stages (A @ ib, B @ ib+STEP)
    int a0 = 0, a1 = 0, a2 = 0, a3 = 0, a4 = 0, a5 = 0, a6 = 0, a7 = 0,
        a8 = 0, a9 = 0, a10 = 0, a11 = 0, a12 = 0, a13 = 0, a14 = 0, a15 = 0;
    int b0 = 0, b1 = 0, b2 = 0, b3 = 0, b4 = 0, b5 = 0, b6 = 0, b7 = 0,
        b8 = 0, b9 = 0, b10 = 0, b11 = 0, b12 = 0, b13 = 0, b14 = 0, b15 = 0;
    float4 va = make_float4(0.f, 0.f, 0.f, 0.f), vb = va;
    LOADSET16(a0,a1,a2,a3,a4,a5,a6,a7,a8,a9,a10,a11,a12,a13,a14,a15, va, ib);
    LOADSET16(b0,b1,b2,b3,b4,b5,b6,b7,b8,b9,b10,b11,b12,b13,b14,b15, vb,
              ib + STEP);

    for (;;) {
        PROC16(a0,a1,a2,a3,a4,a5,a6,a7,a8,a9,a10,a11,a12,a13,a14,a15, va,
               ib + 2 * STEP);
        ib += STEP;
        if (ib >= N_) break;
        PROC16(b0,b1,b2,b3,b4,b5,b6,b7,b8,b9,b10,b11,b12,b13,b14,b15, vb,
               ib + 2 * STEP);
        ib += STEP;
        if (ib >= N_) break;
    }
    __syncthreads();

    // merge the 2 pair tables, write one partial record per block
    float* out = partials + (size_t)blk * REC;
    for (int i = tid; i < K_ * D_; i += TPB) {
        int k = i >> 5, d = i & 31;
        float s = 0.f;
#pragma unroll
        for (int w = 0; w < NPAIR; ++w) s += s_tab[w * TABW + k * KROW + d];
        out[i] = s;
    }
    if (tid < K_) {
        float c = 0.f;
#pragma unroll
        for (int w = 0; w < NPAIR; ++w) c += s_cnt[w * K_ + tid];
        out[K_ * D_ + tid] = c;
    }
}

// ---------------------------------------------------------------------------
// Stage 2a: two-level reduction, level 1 (r9-proven). Grid = B_ * nch blocks;
// block (b, ch) sums rpc records into part2[b*nch+ch]. Thread t owns quads
// {t, t+256, (t<16: t+512)} in NAMED registers.
// ---------------------------------------------------------------------------
__global__ __launch_bounds__(TPB) void seg_reduce_a(
    const float* __restrict__ partials, float* __restrict__ part2,
    int rpc, int nch)
{
    const int blk = blockIdx.x;
    const int b   = blk / nch;
    const int ch  = blk - b * nch;
    const int tid = threadIdx.x;

    const float4* __restrict__ p4 = reinterpret_cast<const float4*>(partials)
        + (size_t)((b * nch + ch) * rpc) * RECQ;
    float4* __restrict__ o4 = reinterpret_cast<float4*>(part2)
        + (size_t)blk * RECQ;

    float4 acc0 = make_float4(0.f, 0.f, 0.f, 0.f);
    float4 acc1 = acc0, acc2 = acc0;
#pragma unroll 4
    for (int r = 0; r < rpc; ++r) {
        const float4* rp = p4 + (size_t)r * RECQ;
        float4 v0 = rp[tid];
        float4 v1 = rp[tid + 256];
        acc0.x += v0.x; acc0.y += v0.y; acc0.z += v0.z; acc0.w += v0.w;
        acc1.x += v1.x; acc1.y += v1.y; acc1.z += v1.z; acc1.w += v1.w;
        if (tid < 16) {
            float4 v2 = rp[tid + 512];
            acc2.x += v2.x; acc2.y += v2.y; acc2.z += v2.z; acc2.w += v2.w;
        }
    }
    o4[tid]       = acc0;
    o4[tid + 256] = acc1;
    if (tid < 16) o4[tid + 512] = acc2;
}

// ---------------------------------------------------------------------------
// Stage 2b+3: one block per batch (r9-proven). Prologue sums the batch's nch
// chunk partials, then scatter to transposed s_cent4[j][k], normalize,
// pair loss, write batch_loss[b].
// ---------------------------------------------------------------------------
__global__ __launch_bounds__(TPB) void loss8_kernel(
    const float* __restrict__ part2, float* __restrict__ batch_loss,
    int nch)
{
    __shared__ __align__(16) float4 s_cent4[8 * K_];  // [j][k]
    __shared__ float s_cntsh[K_];
    __shared__ float s_pres[K_];
    __shared__ float s_wred[NWAVE];

    const int b   = blockIdx.x;
    const int tid = threadIdx.x;
    const float4* __restrict__ p4 = reinterpret_cast<const float4*>(part2)
        + (size_t)(b * nch) * RECQ;

    float4 acc0 = make_float4(0.f, 0.f, 0.f, 0.f);
    float4 acc1 = acc0, acc2 = acc0;
#pragma unroll 8
    for (int c = 0; c < nch; ++c) {
        const float4* rp = p4 + (size_t)c * RECQ;
        float4 v0 = rp[tid];
        float4 v1 = rp[tid + 256];
        acc0.x += v0.x; acc0.y += v0.y; acc0.z += v0.z; acc0.w += v0.w;
        acc1.x += v1.x; acc1.y += v1.y; acc1.z += v1.z; acc1.w += v1.w;
        if (tid < 16) {
            float4 v2 = rp[tid + 512];
            acc2.x += v2.x; acc2.y += v2.y; acc2.z += v2.z; acc2.w += v2.w;
        }
    }

    // scatter: quad q (<512) -> s_cent4[(q&7)*64 + (q>>3)]
    s_cent4[(tid & 7) * K_ + (tid >> 3)] = acc0;
    {
        const int q1 = tid + 256;
        s_cent4[(q1 & 7) * K_ + (q1 >> 3)] = acc1;
    }
    if (tid < 16) reinterpret_cast<float4*>(s_cntsh)[tid] = acc2;
    __syncthreads();

    if (tid < K_) s_pres[tid] = (s_cntsh[tid] > 0.5f) ? 1.f : 0.f;
    for (int i = tid; i < 8 * K_; i += TPB) {
        float inv = 1.0f / fmaxf(s_cntsh[i & 63], 1.0f);
        float4 c = s_cent4[i];
        c.x *= inv; c.y *= inv; c.z *= inv; c.w *= inv;
        s_cent4[i] = c;
    }
    __syncthreads();

    const int wave = tid >> 6, lane = tid & 63;

    float4 cb[8];
#pragma unroll
    for (int j = 0; j < 8; ++j) cb[j] = s_cent4[j * K_ + lane];
    const float pres2 = s_pres[lane];

    float acc = 0.f;
#pragma unroll 4
    for (int t = 0; t < 16; ++t) {
        const int k1 = wave * 16 + t;
        float dist = 0.f;
#pragma unroll
        for (int j = 0; j < 8; ++j) {
            float4 a = s_cent4[j * K_ + k1];   // wave-uniform broadcast
            dist += fabsf(a.x - cb[j].x) + fabsf(a.y - cb[j].y)
                  + fabsf(a.z - cb[j].z) + fabsf(a.w - cb[j].w);
        }
        float h = fmaxf(0.25f - dist, 0.f);
        float valid = (k1 < lane) ? s_pres[k1] * pres2 : 0.f;
        acc += valid * h * h;
    }
#pragma unroll
    for (int m = 32; m > 0; m >>= 1) acc += __shfl_xor(acc, m);
    if (lane == 0) s_wred[wave] = acc;
    __syncthreads();
    if (tid == 0) {
        float s = s_wred[0] + s_wred[1] + s_wred[2] + s_wred[3];
        float n = 0.f;
        for (int k = 0; k < K_; ++k) n += s_pres[k];
        float ncomp = n * (n - 1.f) * 0.5f;
        batch_loss[b] = (ncomp > 0.f) ? (s / ncomp) : 0.f;
    }
}

// ---------------------------------------------------------------------------
// Stage 4: average the 8 per-batch losses into out[0].
// ---------------------------------------------------------------------------
__global__ void final_kernel(const float* __restrict__ batch_loss,
                             float* __restrict__ out)
{
    if (threadIdx.x == 0) {
        float t = 0.f;
#pragma unroll
        for (int b = 0; b < B_; ++b) t += batch_loss[b];
        out[0] = t * (1.0f / (float)B_);
    }
}

// ---------------------------------------------------------------------------
extern "C" void kernel_launch(void* const* d_in, const int* in_sizes, int n_in,
                              void* d_out, int out_size, void* d_ws, size_t ws_size,
                              hipStream_t stream)
{
    const float* emb = (const float*)d_in[0];
    const int*   lab = (const int*)d_in[1];
    float*       out = (float*)d_out;
    float*       ws  = (float*)d_ws;

    // 2048 blocks = 8 resident blocks/CU x 256 CUs at the new 19 KB LDS/block.
    int blk_per_b = 256;
    while (blk_per_b > 8) {
        size_t need = ((size_t)(blk_per_b * B_) * REC          // partials
                       + (size_t)(B_ * 8) * REC                // part2 (max)
                       + B_) * sizeof(float);
        if (need <= ws_size) break;
        blk_per_b >>= 1;
    }
    const int nblk = blk_per_b * B_;
    const int nch  = (blk_per_b >= 8) ? 8 : blk_per_b;
    const int rpc  = blk_per_b / nch;

    float* partials   = ws;
    float* part2      = ws + (size_t)nblk * REC;
    float* batch_loss = part2 + (size_t)(B_ * nch) * REC;

    seg_partial_kernel<<<nblk, TPB, 0, stream>>>(emb, lab, partials, blk_per_b);

    seg_reduce_a<<<B_ * nch, TPB, 0, stream>>>(partials, part2, rpc, nch);

    loss8_kernel<<<B_, TPB, 0, stream>>>(part2, batch_loss, nch);

    final_kernel<<<1, 64, 0, stream>>>(batch_loss, out);
}

// Round 11
// 76.359 us; speedup vs baseline: 1.4077x; 1.4077x over previous
//
#include <hip/hip_runtime.h>

// Problem constants (fixed by setup_inputs): B=8, H=W=512, D=32, K=64
#define B_    8
#define N_    (512 * 512)
#define D_    32
#define K_    64
#define TPB   256
#define NWAVE (TPB / 64)
#define KROW  36                 // row stride (floats): 16B-aligned, spreads banks
#define TABW  (K_ * KROW)        // 2304 floats per wave-private table
#define REC   (K_ * D_ + K_)     // per-block partial record: 2048 sums + 64 counts
#define RECQ  (REC / 4)          // 528 float4 quads per record

// ---------------------------------------------------------------------------
// Stage 1: per-block partial segment sums (r9 structure; ONE change: each
// block reads a CONTIGUOUS element range instead of STEP-strided chunks —
// pure sequential DRAM streams like the 7 TB/s fill kernels).
// Straight-line duplicate handling + 2-deep pipeline with macro-expanded
// NAMED registers (r4 scratch lesson). order==0 lane does the plain float4
// RMW and adds the whole group's count; order>0 lanes (~4%) issue ds_add
// atomics AFTER the write in program order (same-wave LDS ops complete in
// issue order -> race-free).
// ---------------------------------------------------------------------------
#define PROC(L0,L1,L2,L3,L4,L5,L6,L7, V, PBASE)                               \
  {                                                                           \
    int lb = egl < 4 ? (egl < 2 ? (egl == 0 ? L0 : L1)                        \
                                : (egl == 2 ? L2 : L3))                       \
                     : (egl < 6 ? (egl == 4 ? L4 : L5)                        \
                                : (egl == 6 ? L6 : L7));                      \
    const int m0 = (lb == L0), m1 = (lb == L1), m2 = (lb == L2),              \
              m3 = (lb == L3), m4 = (lb == L4), m5 = (lb == L5),              \
              m6 = (lb == L6), m7 = (lb == L7);                               \
    const int order = (g0 & m0) + (g1 & m1) + (g2 & m2) + (g3 & m3) +         \
                      (g4 & m4) + (g5 & m5) + (g6 & m6);                      \
    const int nsame = m0 + m1 + m2 + m3 + m4 + m5 + m6 + m7;                  \
    const float4 vc = V;                                                      \
    const int pb = (PBASE);                                                   \
    if (pb < iend) {      /* uniform branch (block-local bound) */            \
      const int* lp = lab + bbase + pb + wb;   /* wave-uniform -> s_load */   \
      L0 = lp[0]; L1 = lp[1]; L2 = lp[2]; L3 = lp[3];                         \
      L4 = lp[4]; L5 = lp[5]; L6 = lp[6]; L7 = lp[7];                         \
      V = embv[(bbase + pb + eg) * 8 + d4];                                   \
    }                                                                         \
    const int a = lb * KROW + d4 * 4;                                         \
    if (order == 0) {                                                         \
      float4 cur = *reinterpret_cast<const float4*>(tab + a);                 \
      cur.x += vc.x; cur.y += vc.y; cur.z += vc.z; cur.w += vc.w;             \
      *reinterpret_cast<float4*>(tab + a) = cur;                              \
      if (d4 == 0) cnt[lb] += (float)nsame;                                   \
    } else {  /* rare; lands after the write in issue order */                \
      atomicAdd(&tab[a + 0], vc.x);                                           \
      atomicAdd(&tab[a + 1], vc.y);                                           \
      atomicAdd(&tab[a + 2], vc.z);                                           \
      atomicAdd(&tab[a + 3], vc.w);                                           \
    }                                                                         \
  }

__global__ __launch_bounds__(TPB) void seg_partial_kernel(
    const float* __restrict__ emb, const int* __restrict__ lab,
    float* __restrict__ partials, int blk_per_b)
{
    __shared__ __align__(16) float s_tab[NWAVE * TABW];
    __shared__ float s_cnt[NWAVE * K_];

    for (int i = threadIdx.x; i < NWAVE * TABW; i += TPB) s_tab[i] = 0.f;
    for (int i = threadIdx.x; i < NWAVE * K_;  i += TPB) s_cnt[i] = 0.f;
    __syncthreads();

    const int tid  = threadIdx.x;
    const int wave = tid >> 6;
    const int lane = tid & 63;
    const int egl  = lane >> 3;          // element slot within wave: 0..7
    const int d4   = lane & 7;           // float4 slice within element: 0..7
    const int eg   = wave * 8 + egl;     // element slot within block-iter: 0..31

    const int g0 = (0 < egl), g1 = (1 < egl), g2 = (2 < egl), g3 = (3 < egl),
              g4 = (4 < egl), g5 = (5 < egl), g6 = (6 < egl);

    float* __restrict__ tab = s_tab + wave * TABW;
    float* __restrict__ cnt = s_cnt + wave * K_;

    const int blk = blockIdx.x;
    const int b   = blk / blk_per_b;
    const int bib = blk - b * blk_per_b;
    const long long bbase = (long long)b * N_;
    const float4* __restrict__ embv = reinterpret_cast<const float4*>(emb);
    const int CHUNK = N_ / blk_per_b;    // contiguous elements per block
    const int wb = __builtin_amdgcn_readfirstlane(wave * 8);

    int ib = bib * CHUNK;
    const int iend = ib + CHUNK;

    // prologue: fill both pipeline stages (A @ ib, B @ ib+32)
    int a0, a1, a2, a3, a4, a5, a6, a7;
    float4 va;
    {
        const int* lp = lab + bbase + ib + wb;
        a0 = lp[0]; a1 = lp[1]; a2 = lp[2]; a3 = lp[3];
        a4 = lp[4]; a5 = lp[5]; a6 = lp[6]; a7 = lp[7];
        va = embv[(bbase + ib + eg) * 8 + d4];
    }
    int b0 = 0, b1 = 0, b2 = 0, b3 = 0, b4 = 0, b5 = 0, b6 = 0, b7 = 0;
    float4 vb = make_float4(0.f, 0.f, 0.f, 0.f);
    if (ib + 32 < iend) {
        const int* lp = lab + bbase + ib + 32 + wb;
        b0 = lp[0]; b1 = lp[1]; b2 = lp[2]; b3 = lp[3];
        b4 = lp[4]; b5 = lp[5]; b6 = lp[6]; b7 = lp[7];
        vb = embv[(bbase + ib + 32 + eg) * 8 + d4];
    }

    for (;;) {
        PROC(a0, a1, a2, a3, a4, a5, a6, a7, va, ib + 64);
        ib += 32;
        if (ib >= iend) break;
        PROC(b0, b1, b2, b3, b4, b5, b6, b7, vb, ib + 64);
        ib += 32;
        if (ib >= iend) break;
    }
    __syncthreads();

    // merge the 4 wave tables, write one partial record per block
    float* out = partials + (size_t)blk * REC;
    for (int i = tid; i < K_ * D_; i += TPB) {
        int k = i >> 5, d = i & 31;
        float s = 0.f;
#pragma unroll
        for (int w = 0; w < NWAVE; ++w) s += s_tab[w * TABW + k * KROW + d];
        out[i] = s;
    }
    if (tid < K_) {
        float c = 0.f;
#pragma unroll
        for (int w = 0; w < NWAVE; ++w) c += s_cnt[w * K_ + tid];
        out[K_ * D_ + tid] = c;
    }
}

// ---------------------------------------------------------------------------
// Stage 2a: two-level reduction, level 1 (r9-proven). Grid = B_ * nch blocks;
// block (b, ch) sums rpc records into part2[b*nch+ch]. Thread t owns quads
// {t, t+256, (t<16: t+512)} in NAMED registers.
// ---------------------------------------------------------------------------
__global__ __launch_bounds__(TPB) void seg_reduce_a(
    const float* __restrict__ partials, float* __restrict__ part2,
    int rpc, int nch)
{
    const int blk = blockIdx.x;
    const int b   = blk / nch;
    const int ch  = blk - b * nch;
    const int tid = threadIdx.x;

    const float4* __restrict__ p4 = reinterpret_cast<const float4*>(partials)
        + (size_t)((b * nch + ch) * rpc) * RECQ;
    float4* __restrict__ o4 = reinterpret_cast<float4*>(part2)
        + (size_t)blk * RECQ;

    float4 acc0 = make_float4(0.f, 0.f, 0.f, 0.f);
    float4 acc1 = acc0, acc2 = acc0;
#pragma unroll 4
    for (int r = 0; r < rpc; ++r) {
        const float4* rp = p4 + (size_t)r * RECQ;
        float4 v0 = rp[tid];
        float4 v1 = rp[tid + 256];
        acc0.x += v0.x; acc0.y += v0.y; acc0.z += v0.z; acc0.w += v0.w;
        acc1.x += v1.x; acc1.y += v1.y; acc1.z += v1.z; acc1.w += v1.w;
        if (tid < 16) {
            float4 v2 = rp[tid + 512];
            acc2.x += v2.x; acc2.y += v2.y; acc2.z += v2.z; acc2.w += v2.w;
        }
    }
    o4[tid]       = acc0;
    o4[tid + 256] = acc1;
    if (tid < 16) o4[tid + 512] = acc2;
}

// ---------------------------------------------------------------------------
// Stage 2b+3: one block per batch (r9-proven). Prologue sums the batch's nch
// chunk partials, then scatter to transposed s_cent4[j][k], normalize,
// pair loss, write batch_loss[b].
// ---------------------------------------------------------------------------
__global__ __launch_bounds__(TPB) void loss8_kernel(
    const float* __restrict__ part2, float* __restrict__ batch_loss,
    int nch)
{
    __shared__ __align__(16) float4 s_cent4[8 * K_];  // [j][k]
    __shared__ float s_cntsh[K_];
    __shared__ float s_pres[K_];
    __shared__ float s_wred[NWAVE];

    const int b   = blockIdx.x;
    const int tid = threadIdx.x;
    const float4* __restrict__ p4 = reinterpret_cast<const float4*>(part2)
        + (size_t)(b * nch) * RECQ;

    float4 acc0 = make_float4(0.f, 0.f, 0.f, 0.f);
    float4 acc1 = acc0, acc2 = acc0;
#pragma unroll 8
    for (int c = 0; c < nch; ++c) {
        const float4* rp = p4 + (size_t)c * RECQ;
        float4 v0 = rp[tid];
        float4 v1 = rp[tid + 256];
        acc0.x += v0.x; acc0.y += v0.y; acc0.z += v0.z; acc0.w += v0.w;
        acc1.x += v1.x; acc1.y += v1.y; acc1.z += v1.z; acc1.w += v1.w;
        if (tid < 16) {
            float4 v2 = rp[tid + 512];
            acc2.x += v2.x; acc2.y += v2.y; acc2.z += v2.z; acc2.w += v2.w;
        }
    }

    // scatter: quad q (<512) -> s_cent4[(q&7)*64 + (q>>3)]
    s_cent4[(tid & 7) * K_ + (tid >> 3)] = acc0;
    {
        const int q1 = tid + 256;
        s_cent4[(q1 & 7) * K_ + (q1 >> 3)] = acc1;
    }
    if (tid < 16) reinterpret_cast<float4*>(s_cntsh)[tid] = acc2;
    __syncthreads();

    if (tid < K_) s_pres[tid] = (s_cntsh[tid] > 0.5f) ? 1.f : 0.f;
    for (int i = tid; i < 8 * K_; i += TPB) {
        float inv = 1.0f / fmaxf(s_cntsh[i & 63], 1.0f);
        float4 c = s_cent4[i];
        c.x *= inv; c.y *= inv; c.z *= inv; c.w *= inv;
        s_cent4[i] = c;
    }
    __syncthreads();

    const int wave = tid >> 6, lane = tid & 63;

    float4 cb[8];
#pragma unroll
    for (int j = 0; j < 8; ++j) cb[j] = s_cent4[j * K_ + lane];
    const float pres2 = s_pres[lane];

    float acc = 0.f;
#pragma unroll 4
    for (int t = 0; t < 16; ++t) {
        const int k1 = wave * 16 + t;
        float dist = 0.f;
#pragma unroll
        for (int j = 0; j < 8; ++j) {
            float4 a = s_cent4[j * K_ + k1];   // wave-uniform broadcast
            dist += fabsf(a.x - cb[j].x) + fabsf(a.y - cb[j].y)
                  + fabsf(a.z - cb[j].z) + fabsf(a.w - cb[j].w);
        }
        float h = fmaxf(0.25f - dist, 0.f);
        float valid = (k1 < lane) ? s_pres[k1] * pres2 : 0.f;
        acc += valid * h * h;
    }
#pragma unroll
    for (int m = 32; m > 0; m >>= 1) acc += __shfl_xor(acc, m);
    if (lane == 0) s_wred[wave] = acc;
    __syncthreads();
    if (tid == 0) {
        float s = s_wred[0] + s_wred[1] + s_wred[2] + s_wred[3];
        float n = 0.f;
        for (int k = 0; k < K_; ++k) n += s_pres[k];
        float ncomp = n * (n - 1.f) * 0.5f;
        batch_loss[b] = (ncomp > 0.f) ? (s / ncomp) : 0.f;
    }
}

// ---------------------------------------------------------------------------
// Stage 4: average the 8 per-batch losses into out[0].
// ---------------------------------------------------------------------------
__global__ void final_kernel(const float* __restrict__ batch_loss,
                             float* __restrict__ out)
{
    if (threadIdx.x == 0) {
        float t = 0.f;
#pragma unroll
        for (int b = 0; b < B_; ++b) t += batch_loss[b];
        out[0] = t * (1.0f / (float)B_);
    }
}

// ---------------------------------------------------------------------------
extern "C" void kernel_launch(void* const* d_in, const int* in_sizes, int n_in,
                              void* d_out, int out_size, void* d_ws, size_t ws_size,
                              hipStream_t stream)
{
    const float* emb = (const float*)d_in[0];
    const int*   lab = (const int*)d_in[1];
    float*       out = (float*)d_out;
    float*       ws  = (float*)d_ws;

    int blk_per_b = 128;
    while (blk_per_b > 8) {
        size_t need = ((size_t)(blk_per_b * B_) * REC          // partials
                       + (size_t)(B_ * 8) * REC                // part2 (max)
                       + B_) * sizeof(float);
        if (need <= ws_size) break;
        blk_per_b >>= 1;
    }
    const int nblk = blk_per_b * B_;
    const int nch  = (blk_per_b >= 8) ? 8 : blk_per_b;
    const int rpc  = blk_per_b / nch;

    float* partials   = ws;
    float* part2      = ws + (size_t)nblk * REC;
    float* batch_loss = part2 + (size_t)(B_ * nch) * REC;

    seg_partial_kernel<<<nblk, TPB, 0, stream>>>(emb, lab, partials, blk_per_b);

    seg_reduce_a<<<B_ * nch, TPB, 0, stream>>>(partials, part2, rpc, nch);

    loss8_kernel<<<B_, TPB, 0, stream>>>(part2, batch_loss, nch);

    final_kernel<<<1, 64, 0, stream>>>(batch_loss, out);
}

// Round 12
// 74.560 us; speedup vs baseline: 1.4416x; 1.0241x over previous
//
#include <hip/hip_runtime.h>

// Problem constants (fixed by setup_inputs): B=8, H=W=512, D=32, K=64
#define B_    8
#define N_    (512 * 512)
#define D_    32
#define K_    64
#define TPB   256
#define NWAVE (TPB / 64)
#define KROW  36                 // row stride (floats): 16B-aligned, spreads banks
#define TABW  (K_ * KROW)        // 2304 floats per wave-private table
#define REC   (K_ * D_ + K_)     // per-block partial record: 2048 sums + 64 counts
#define RECQ  (REC / 4)          // 528 float4 quads per record
#define SEG   512                // labels staged per segment (2 KB LDS)

// ---------------------------------------------------------------------------
// Stage 1: per-block partial segment sums. KEY CHANGE vs r9/r11: NO SMEM in
// the hot loop. Wave-uniform label loads compiled to s_load (SMEM); SMEM
// returns out-of-order, so every table-ds_read use forced lgkmcnt(0) --
// draining the just-issued label prefetch at L2 latency EVERY iteration
// (explains r7's 4-deep null and r11's pattern null). Labels are now bulk-
// staged into LDS per 512-element segment and read as broadcast b128 --
// in-order DS domain, short counted waits; embv float4 stays vmcnt-domain
// 2-deep prefetched. Duplicate handling + macro-named registers as proven.
// ---------------------------------------------------------------------------
#define PROC(L0,L1,L2,L3,L4,L5,L6,L7, V, PBASE)                               \
  {                                                                           \
    int lb = egl < 4 ? (egl < 2 ? (egl == 0 ? L0 : L1)                        \
                                : (egl == 2 ? L2 : L3))                       \
                     : (egl < 6 ? (egl == 4 ? L4 : L5)                        \
                                : (egl == 6 ? L6 : L7));                      \
    const int m0 = (lb == L0), m1 = (lb == L1), m2 = (lb == L2),              \
              m3 = (lb == L3), m4 = (lb == L4), m5 = (lb == L5),              \
              m6 = (lb == L6), m7 = (lb == L7);                               \
    const int order = (g0 & m0) + (g1 & m1) + (g2 & m2) + (g3 & m3) +         \
                      (g4 & m4) + (g5 & m5) + (g6 & m6);                      \
    const int nsame = m0 + m1 + m2 + m3 + m4 + m5 + m6 + m7;                  \
    const float4 vc = V;                                                      \
    const int pb = (PBASE);                                                   \
    if (pb < send) {      /* uniform branch (segment bound) */                \
      const int4* lq = reinterpret_cast<const int4*>(s_lab + (pb - sbeg) + wb);\
      int4 u0 = lq[0];    /* ds_read_b128 broadcast (in-order DS) */          \
      int4 u1 = lq[1];                                                        \
      L0 = u0.x; L1 = u0.y; L2 = u0.z; L3 = u0.w;                             \
      L4 = u1.x; L5 = u1.y; L6 = u1.z; L7 = u1.w;                             \
      V = embv[(bbase + pb + eg) * 8 + d4];   /* global, vmcnt domain */      \
    }                                                                         \
    const int a = lb * KROW + d4 * 4;                                         \
    if (order == 0) {                                                         \
      float4 cur = *reinterpret_cast<const float4*>(tab + a);                 \
      cur.x += vc.x; cur.y += vc.y; cur.z += vc.z; cur.w += vc.w;             \
      *reinterpret_cast<float4*>(tab + a) = cur;                              \
      if (d4 == 0) cnt[lb] += (float)nsame;                                   \
    } else {  /* rare; lands after the write in issue order */                \
      atomicAdd(&tab[a + 0], vc.x);                                           \
      atomicAdd(&tab[a + 1], vc.y);                                           \
      atomicAdd(&tab[a + 2], vc.z);                                           \
      atomicAdd(&tab[a + 3], vc.w);                                           \
    }                                                                         \
  }

__global__ __launch_bounds__(TPB) void seg_partial_kernel(
    const float* __restrict__ emb, const int* __restrict__ lab,
    float* __restrict__ partials, int blk_per_b)
{
    __shared__ __align__(16) float s_tab[NWAVE * TABW];
    __shared__ float s_cnt[NWAVE * K_];
    __shared__ __align__(16) int s_lab[SEG];

    for (int i = threadIdx.x; i < NWAVE * TABW; i += TPB) s_tab[i] = 0.f;
    for (int i = threadIdx.x; i < NWAVE * K_;  i += TPB) s_cnt[i] = 0.f;

    const int tid  = threadIdx.x;
    const int wave = tid >> 6;
    const int lane = tid & 63;
    const int egl  = lane >> 3;          // element slot within wave: 0..7
    const int d4   = lane & 7;           // float4 slice within element: 0..7
    const int eg   = wave * 8 + egl;     // element slot within block-iter: 0..31

    const int g0 = (0 < egl), g1 = (1 < egl), g2 = (2 < egl), g3 = (3 < egl),
              g4 = (4 < egl), g5 = (5 < egl), g6 = (6 < egl);

    float* __restrict__ tab = s_tab + wave * TABW;
    float* __restrict__ cnt = s_cnt + wave * K_;

    const int blk = blockIdx.x;
    const int b   = blk / blk_per_b;
    const int bib = blk - b * blk_per_b;
    const long long bbase = (long long)b * N_;
    const float4* __restrict__ embv = reinterpret_cast<const float4*>(emb);
    const int CHUNK = N_ / blk_per_b;    // contiguous elements per block
    const int wb = __builtin_amdgcn_readfirstlane(wave * 8);

    const int cstart = bib * CHUNK;
    const int cend   = cstart + CHUNK;

    for (int sbeg = cstart; sbeg < cend; sbeg += SEG) {
        const int send = (sbeg + SEG < cend) ? sbeg + SEG : cend;
        __syncthreads();   // protect s_lab from previous segment's readers
        {
            const int nq = (send - sbeg) >> 2;
            const int4* gq = reinterpret_cast<const int4*>(lab + bbase + sbeg);
            int4* sq = reinterpret_cast<int4*>(s_lab);
            for (int q = tid; q < nq; q += TPB) sq[q] = gq[q];
        }
        __syncthreads();

        int ib = sbeg;
        // segment prologue: fill both pipeline stages (A @ ib, B @ ib+32)
        int a0, a1, a2, a3, a4, a5, a6, a7;
        float4 va;
        {
            const int4* lq = reinterpret_cast<const int4*>(s_lab + (ib - sbeg) + wb);
            int4 u0 = lq[0], u1 = lq[1];
            a0 = u0.x; a1 = u0.y; a2 = u0.z; a3 = u0.w;
            a4 = u1.x; a5 = u1.y; a6 = u1.z; a7 = u1.w;
            va = embv[(bbase + ib + eg) * 8 + d4];
        }
        int b0 = 0, b1 = 0, b2 = 0, b3 = 0, b4 = 0, b5 = 0, b6 = 0, b7 = 0;
        float4 vb = make_float4(0.f, 0.f, 0.f, 0.f);
        if (ib + 32 < send) {
            const int4* lq = reinterpret_cast<const int4*>(s_lab + (ib + 32 - sbeg) + wb);
            int4 u0 = lq[0], u1 = lq[1];
            b0 = u0.x; b1 = u0.y; b2 = u0.z; b3 = u0.w;
            b4 = u1.x; b5 = u1.y; b6 = u1.z; b7 = u1.w;
            vb = embv[(bbase + ib + 32 + eg) * 8 + d4];
        }

        for (;;) {
            PROC(a0, a1, a2, a3, a4, a5, a6, a7, va, ib + 64);
            ib += 32;
            if (ib >= send) break;
            PROC(b0, b1, b2, b3, b4, b5, b6, b7, vb, ib + 64);
            ib += 32;
            if (ib >= send) break;
        }
    }
    __syncthreads();

    // merge the 4 wave tables, write one partial record per block
    float* out = partials + (size_t)blk * REC;
    for (int i = tid; i < K_ * D_; i += TPB) {
        int k = i >> 5, d = i & 31;
        float s = 0.f;
#pragma unroll
        for (int w = 0; w < NWAVE; ++w) s += s_tab[w * TABW + k * KROW + d];
        out[i] = s;
    }
    if (tid < K_) {
        float c = 0.f;
#pragma unroll
        for (int w = 0; w < NWAVE; ++w) c += s_cnt[w * K_ + tid];
        out[K_ * D_ + tid] = c;
    }
}

// ---------------------------------------------------------------------------
// Stage 2a: two-level reduction, level 1 (r9-proven).
// ---------------------------------------------------------------------------
__global__ __launch_bounds__(TPB) void seg_reduce_a(
    const float* __restrict__ partials, float* __restrict__ part2,
    int rpc, int nch)
{
    const int blk = blockIdx.x;
    const int b   = blk / nch;
    const int ch  = blk - b * nch;
    const int tid = threadIdx.x;

    const float4* __restrict__ p4 = reinterpret_cast<const float4*>(partials)
        + (size_t)((b * nch + ch) * rpc) * RECQ;
    float4* __restrict__ o4 = reinterpret_cast<float4*>(part2)
        + (size_t)blk * RECQ;

    float4 acc0 = make_float4(0.f, 0.f, 0.f, 0.f);
    float4 acc1 = acc0, acc2 = acc0;
#pragma unroll 4
    for (int r = 0; r < rpc; ++r) {
        const float4* rp = p4 + (size_t)r * RECQ;
        float4 v0 = rp[tid];
        float4 v1 = rp[tid + 256];
        acc0.x += v0.x; acc0.y += v0.y; acc0.z += v0.z; acc0.w += v0.w;
        acc1.x += v1.x; acc1.y += v1.y; acc1.z += v1.z; acc1.w += v1.w;
        if (tid < 16) {
            float4 v2 = rp[tid + 512];
            acc2.x += v2.x; acc2.y += v2.y; acc2.z += v2.z; acc2.w += v2.w;
        }
    }
    o4[tid]       = acc0;
    o4[tid + 256] = acc1;
    if (tid < 16) o4[tid + 512] = acc2;
}

// ---------------------------------------------------------------------------
// Stage 2b+3: one block per batch (r9-proven).
// ---------------------------------------------------------------------------
__global__ __launch_bounds__(TPB) void loss8_kernel(
    const float* __restrict__ part2, float* __restrict__ batch_loss,
    int nch)
{
    __shared__ __align__(16) float4 s_cent4[8 * K_];  // [j][k]
    __shared__ float s_cntsh[K_];
    __shared__ float s_pres[K_];
    __shared__ float s_wred[NWAVE];

    const int b   = blockIdx.x;
    const int tid = threadIdx.x;
    const float4* __restrict__ p4 = reinterpret_cast<const float4*>(part2)
        + (size_t)(b * nch) * RECQ;

    float4 acc0 = make_float4(0.f, 0.f, 0.f, 0.f);
    float4 acc1 = acc0, acc2 = acc0;
#pragma unroll 8
    for (int c = 0; c < nch; ++c) {
        const float4* rp = p4 + (size_t)c * RECQ;
        float4 v0 = rp[tid];
        float4 v1 = rp[tid + 256];
        acc0.x += v0.x; acc0.y += v0.y; acc0.z += v0.z; acc0.w += v0.w;
        acc1.x += v1.x; acc1.y += v1.y; acc1.z += v1.z; acc1.w += v1.w;
        if (tid < 16) {
            float4 v2 = rp[tid + 512];
            acc2.x += v2.x; acc2.y += v2.y; acc2.z += v2.z; acc2.w += v2.w;
        }
    }

    // scatter: quad q (<512) -> s_cent4[(q&7)*64 + (q>>3)]
    s_cent4[(tid & 7) * K_ + (tid >> 3)] = acc0;
    {
        const int q1 = tid + 256;
        s_cent4[(q1 & 7) * K_ + (q1 >> 3)] = acc1;
    }
    if (tid < 16) reinterpret_cast<float4*>(s_cntsh)[tid] = acc2;
    __syncthreads();

    if (tid < K_) s_pres[tid] = (s_cntsh[tid] > 0.5f) ? 1.f : 0.f;
    for (int i = tid; i < 8 * K_; i += TPB) {
        float inv = 1.0f / fmaxf(s_cntsh[i & 63], 1.0f);
        float4 c = s_cent4[i];
        c.x *= inv; c.y *= inv; c.z *= inv; c.w *= inv;
        s_cent4[i] = c;
    }
    __syncthreads();

    const int wave = tid >> 6, lane = tid & 63;

    float4 cb[8];
#pragma unroll
    for (int j = 0; j < 8; ++j) cb[j] = s_cent4[j * K_ + lane];
    const float pres2 = s_pres[lane];

    float acc = 0.f;
#pragma unroll 4
    for (int t = 0; t < 16; ++t) {
        const int k1 = wave * 16 + t;
        float dist = 0.f;
#pragma unroll
        for (int j = 0; j < 8; ++j) {
            float4 a = s_cent4[j * K_ + k1];   // wave-uniform broadcast
            dist += fabsf(a.x - cb[j].x) + fabsf(a.y - cb[j].y)
                  + fabsf(a.z - cb[j].z) + fabsf(a.w - cb[j].w);
        }
        float h = fmaxf(0.25f - dist, 0.f);
        float valid = (k1 < lane) ? s_pres[k1] * pres2 : 0.f;
        acc += valid * h * h;
    }
#pragma unroll
    for (int m = 32; m > 0; m >>= 1) acc += __shfl_xor(acc, m);
    if (lane == 0) s_wred[wave] = acc;
    __syncthreads();
    if (tid == 0) {
        float s = s_wred[0] + s_wred[1] + s_wred[2] + s_wred[3];
        float n = 0.f;
        for (int k = 0; k < K_; ++k) n += s_pres[k];
        float ncomp = n * (n - 1.f) * 0.5f;
        batch_loss[b] = (ncomp > 0.f) ? (s / ncomp) : 0.f;
    }
}

// ---------------------------------------------------------------------------
// Stage 4: average the 8 per-batch losses into out[0].
// ---------------------------------------------------------------------------
__global__ void final_kernel(const float* __restrict__ batch_loss,
                             float* __restrict__ out)
{
    if (threadIdx.x == 0) {
        float t = 0.f;
#pragma unroll
        for (int b = 0; b < B_; ++b) t += batch_loss[b];
        out[0] = t * (1.0f / (float)B_);
    }
}

// ---------------------------------------------------------------------------
extern "C" void kernel_launch(void* const* d_in, const int* in_sizes, int n_in,
                              void* d_out, int out_size, void* d_ws, size_t ws_size,
                              hipStream_t stream)
{
    const float* emb = (const float*)d_in[0];
    const int*   lab = (const int*)d_in[1];
    float*       out = (float*)d_out;
    float*       ws  = (float*)d_ws;

    int blk_per_b = 128;
    while (blk_per_b > 8) {
        size_t need = ((size_t)(blk_per_b * B_) * REC          // partials
                       + (size_t)(B_ * 8) * REC                // part2 (max)
                       + B_) * sizeof(float);
        if (need <= ws_size) break;
        blk_per_b >>= 1;
    }
    const int nblk = blk_per_b * B_;
    const int nch  = (blk_per_b >= 8) ? 8 : blk_per_b;
    const int rpc  = blk_per_b / nch;

    float* partials   = ws;
    float* part2      = ws + (size_t)nblk * REC;
    float* batch_loss = part2 + (size_t)(B_ * nch) * REC;

    seg_partial_kernel<<<nblk, TPB, 0, stream>>>(emb, lab, partials, blk_per_b);

    seg_reduce_a<<<B_ * nch, TPB, 0, stream>>>(partials, part2, rpc, nch);

    loss8_kernel<<<B_, TPB, 0, stream>>>(part2, batch_loss, nch);

    final_kernel<<<1, 64, 0, stream>>>(batch_loss, out);
}